// Round 1
// baseline (355.275 us; speedup 1.0000x reference)
//
#include <hip/hip_runtime.h>
#include <math.h>

#define B_ 4
#define N_ 1024
#define M_ 2048
#define D_ 9
#define K_ 64
#define BM_ (B_*M_)   // 8192 targets
#define BN_ (B_*N_)   // 4096 preds
#define TPRE_STRIDE 12
#define PPRE_STRIDE 12

// workspace layout (in floats)
#define WS_A 0                                   // 81: cov_inv (symmetric)
#define WS_MEAN 81                               // 9
#define WS_TPRE 96                               // 8192*12: [Au(9), uAu, pad, pad]
#define WS_PPRE (WS_TPRE + BM_*TPRE_STRIDE)      // 4096*12: [Aq(9), qAq, yAy, pad]
#define WS_CS_INTRA (WS_PPRE + BN_*PPRE_STRIDE)  // 1024 per-column sums
#define WS_CS_INTER (WS_CS_INTRA + N_)           // 1024

__device__ __forceinline__ unsigned f2key(float f) {
  unsigned b = __float_as_uint(f);
  return (b & 0x80000000u) ? ~b : (b | 0x80000000u);
}
__device__ __forceinline__ float key2f(unsigned k) {
  unsigned b = (k & 0x80000000u) ? (k ^ 0x80000000u) : ~k;
  return __uint_as_float(b);
}

// mask dtype auto-detect from first 8192 bytes (always in-bounds for
// u8/i32/i64 layouts). 0 = u8/bool, 1 = int32, 2 = int64.
__device__ int detect_mask_fmt(const void* mask, int* flags /*shared[2]*/) {
  int tid = threadIdx.x;
  if (tid < 2) flags[tid] = 0;
  __syncthreads();
  const unsigned char* mb = (const unsigned char*)mask;
  int la = 0, lb = 0;
  for (int i = tid; i < BM_; i += 256) {
    unsigned char c = mb[i];
    if (c) { if (i & 3) la = 1; else if ((i & 7) == 4) lb = 1; }
  }
  if (la) atomicOr(&flags[0], 1);
  if (lb) atomicOr(&flags[1], 1);
  __syncthreads();
  return flags[0] ? 0 : (flags[1] ? 1 : 2);
}
__device__ __forceinline__ int mask_at(const void* mask, int fmt, int t) {
  if (fmt == 0) return ((const unsigned char*)mask)[t] != 0;
  if (fmt == 1) return ((const int*)mask)[t] != 0;
  return ((const long long*)mask)[t] != 0LL;
}

// ---------------- kernel 1: stats (mean, cov, inverse) ----------------
__global__ __launch_bounds__(256) void stats_kernel(
    const float* __restrict__ targets, const void* __restrict__ mask,
    float* __restrict__ ws) {
  __shared__ int flags[2];
  __shared__ double sbuf[256];
  __shared__ double meanS[D_];
  __shared__ double Ssh;
  __shared__ double covp[45];
  int tid = threadIdx.x;
  int fmt = detect_mask_fmt(mask, flags);

  // pass A: S and mean
  double sw = 0.0, st[D_];
  for (int d = 0; d < D_; ++d) st[d] = 0.0;
  for (int t = tid; t < BM_; t += 256) {
    if (mask_at(mask, fmt, t)) {
      sw += 1.0;
      const float* tp = targets + t * D_;
      for (int d = 0; d < D_; ++d) st[d] += (double)tp[d];
    }
  }
  {
    double vals[10];
    vals[0] = sw;
    for (int d = 0; d < D_; ++d) vals[1 + d] = st[d];
    for (int q = 0; q < 10; ++q) {
      sbuf[tid] = vals[q];
      __syncthreads();
      for (int off = 128; off > 0; off >>= 1) {
        if (tid < off) sbuf[tid] += sbuf[tid + off];
        __syncthreads();
      }
      if (tid == 0) {
        if (q == 0) Ssh = sbuf[0];
        else meanS[q - 1] = sbuf[0] / Ssh;
      }
      __syncthreads();
    }
  }

  // pass B: covariance (upper triangle, 45 entries)
  double cv[45];
  for (int p = 0; p < 45; ++p) cv[p] = 0.0;
  for (int t = tid; t < BM_; t += 256) {
    if (mask_at(mask, fmt, t)) {
      const float* tp = targets + t * D_;
      double u[D_];
      for (int d = 0; d < D_; ++d) u[d] = (double)tp[d] - meanS[d];
      int p = 0;
      for (int i = 0; i < D_; ++i)
        for (int j = i; j < D_; ++j, ++p) cv[p] += u[i] * u[j];
    }
  }
  for (int p = 0; p < 45; ++p) {
    sbuf[tid] = cv[p];
    __syncthreads();
    for (int off = 128; off > 0; off >>= 1) {
      if (tid < off) sbuf[tid] += sbuf[tid + off];
      __syncthreads();
    }
    if (tid == 0) covp[p] = sbuf[0];
    __syncthreads();
  }

  if (tid == 0) {
    double Cm[D_][D_], Ai[D_][D_];
    double denom = Ssh - 1.0;
    int p = 0;
    for (int i = 0; i < D_; ++i)
      for (int j = i; j < D_; ++j, ++p) {
        double v = covp[p] / denom;
        Cm[i][j] = v; Cm[j][i] = v;
      }
    for (int i = 0; i < D_; ++i)
      for (int j = 0; j < D_; ++j) Ai[i][j] = (i == j) ? 1.0 : 0.0;
    // Gauss-Jordan with partial pivoting (f64)
    for (int c = 0; c < D_; ++c) {
      int piv = c; double pv = fabs(Cm[c][c]);
      for (int r = c + 1; r < D_; ++r)
        if (fabs(Cm[r][c]) > pv) { pv = fabs(Cm[r][c]); piv = r; }
      if (piv != c) {
        for (int j = 0; j < D_; ++j) {
          double t1 = Cm[c][j]; Cm[c][j] = Cm[piv][j]; Cm[piv][j] = t1;
          t1 = Ai[c][j]; Ai[c][j] = Ai[piv][j]; Ai[piv][j] = t1;
        }
      }
      double inv = 1.0 / Cm[c][c];
      for (int j = 0; j < D_; ++j) { Cm[c][j] *= inv; Ai[c][j] *= inv; }
      for (int r = 0; r < D_; ++r) {
        if (r == c) continue;
        double f = Cm[r][c];
        if (f != 0.0)
          for (int j = 0; j < D_; ++j) {
            Cm[r][j] -= f * Cm[c][j]; Ai[r][j] -= f * Ai[c][j];
          }
      }
    }
    // symmetrize + write
    for (int i = 0; i < D_; ++i)
      for (int j = 0; j < D_; ++j)
        ws[WS_A + i * D_ + j] = (float)(0.5 * (Ai[i][j] + Ai[j][i]));
    for (int d = 0; d < D_; ++d) ws[WS_MEAN + d] = (float)meanS[d];
  }
}

// ---------------- kernel 2: precompute factored terms ----------------
__global__ __launch_bounds__(256) void pre_kernel(
    const float* __restrict__ outputs, const float* __restrict__ targets,
    const void* __restrict__ mask, float* __restrict__ ws) {
  __shared__ int flags[2];
  __shared__ float Ash[81];
  __shared__ float msh[D_];
  int tid = threadIdx.x;
  int fmt = detect_mask_fmt(mask, flags);
  if (tid < 81) Ash[tid] = ws[WS_A + tid];
  if (tid < D_) msh[tid] = ws[WS_MEAN + tid];
  __syncthreads();
  int idx = blockIdx.x * 256 + tid;
  if (idx < BM_) {
    // target side: u = t - mean; store Au, uᵀAu (inf if masked out)
    const float* tp = targets + idx * D_;
    float u[D_];
    for (int d = 0; d < D_; ++d) u[d] = tp[d] - msh[d];
    float cu = 0.f; float au[D_];
    for (int i = 0; i < D_; ++i) {
      float s = 0.f;
      for (int j = 0; j < D_; ++j) s += Ash[i * D_ + j] * u[j];
      au[i] = s; cu += u[i] * s;
    }
    if (!mask_at(mask, fmt, idx)) cu = INFINITY;
    float* o = ws + WS_TPRE + idx * TPRE_STRIDE;
    for (int d = 0; d < D_; ++d) o[d] = au[d];
    o[9] = cu; o[10] = 0.f; o[11] = 0.f;
  } else if (idx < BM_ + BN_) {
    // pred side: q = y + mean; store Aq, qᵀAq, yᵀAy
    int r = idx - BM_;
    const float* yp = outputs + r * D_;
    float y[D_], q[D_], aq[D_];
    for (int d = 0; d < D_; ++d) { y[d] = yp[d]; q[d] = y[d] + msh[d]; }
    float cp = 0.f, cq = 0.f;
    for (int i = 0; i < D_; ++i) {
      float sy = 0.f, sq = 0.f;
      for (int j = 0; j < D_; ++j) {
        sy += Ash[i * D_ + j] * y[j];
        sq += Ash[i * D_ + j] * q[j];
      }
      cp += y[i] * sy;
      aq[i] = sq; cq += q[i] * sq;
    }
    float* o = ws + WS_PPRE + r * PPRE_STRIDE;
    for (int d = 0; d < D_; ++d) o[d] = aq[d];
    o[9] = cq; o[10] = cp; o[11] = 0.f;
  }
}

// ------------- deterministic radix-select: sum of k smallest -------------
template <int V>
__device__ float select_sum_k(const float* vals, int k, unsigned* hist,
                              float* rs, int* rc, unsigned* sprefix, int* skk) {
  int tid = threadIdx.x;
  unsigned prefix = 0;
  int kk = k;
  for (int shift = 24; shift >= 0; shift -= 8) {
    hist[tid] = 0;
    __syncthreads();
    unsigned himask = (shift == 24) ? 0u : (0xFFFFFFFFu << (shift + 8));
    for (int i = tid; i < V; i += 256) {
      unsigned key = f2key(vals[i]);
      if ((key & himask) == prefix)
        atomicAdd(&hist[(key >> shift) & 0xFFu], 1u);
    }
    __syncthreads();
    if (tid == 0) {
      int cum = 0; int bin = 0;
      for (; bin < 255; ++bin) {
        int h = (int)hist[bin];
        if (cum + h >= kk) break;
        cum += h;
      }
      *sprefix = prefix | ((unsigned)bin << shift);
      *skk = kk - cum;
    }
    __syncthreads();
    prefix = *sprefix; kk = *skk;
    __syncthreads();
  }
  unsigned tau = prefix;           // exact key of k-th smallest
  float tauval = key2f(tau);
  float psum = 0.f; int pcnt = 0;
  for (int i = tid; i < V; i += 256) {
    float v = vals[i];
    if (f2key(v) < tau) { psum += v; pcnt++; }
  }
  rs[tid] = psum; rc[tid] = pcnt;
  __syncthreads();
  for (int off = 128; off > 0; off >>= 1) {
    if (tid < off) { rs[tid] += rs[tid + off]; rc[tid] += rc[tid + off]; }
    __syncthreads();
  }
  return rs[0] + (float)(k - rc[0]) * tauval;
}

// ---------------- kernel 3: intra (per-column over 8192 targets) ----------------
__global__ __launch_bounds__(256) void intra_kernel(
    const float* __restrict__ outputs, const float* __restrict__ wsro,
    float* __restrict__ colsum) {
  __shared__ float dist[BM_];
  __shared__ float vsh[B_][D_];
  __shared__ float cvsh[B_];
  __shared__ unsigned hist[256];
  __shared__ float rs[256];
  __shared__ int rc[256];
  __shared__ unsigned sprefix;
  __shared__ int skk;
  int tid = threadIdx.x;
  int n = blockIdx.x;
  if (tid < B_ * D_) {
    int b = tid / D_, d = tid % D_;
    vsh[b][d] = outputs[(b * N_ + n) * D_ + d];
  }
  if (tid < B_) cvsh[tid] = wsro[WS_PPRE + (tid * N_ + n) * PPRE_STRIDE + 10];
  __syncthreads();
  for (int i = tid; i < BM_; i += 256) {
    int b = i >> 11;  // i / M_
    const float4* tp4 = (const float4*)(wsro + WS_TPRE + i * TPRE_STRIDE);
    float4 a0 = tp4[0], a1 = tp4[1], a2 = tp4[2];
    float dot = a0.x * vsh[b][0] + a0.y * vsh[b][1] + a0.z * vsh[b][2] +
                a0.w * vsh[b][3] + a1.x * vsh[b][4] + a1.y * vsh[b][5] +
                a1.z * vsh[b][6] + a1.w * vsh[b][7] + a2.x * vsh[b][8];
    dist[i] = a2.y + cvsh[b] - 2.0f * dot;  // uAu + yAy - 2 uAy
  }
  __syncthreads();
  float s = select_sum_k<BM_>(dist, K_, hist, rs, rc, &sprefix, &skk);
  if (tid == 0) colsum[n] = s;
}

// ---------------- kernel 4: inter (per-column over 4096 preds) ----------------
__global__ __launch_bounds__(256) void inter_kernel(
    const float* __restrict__ outputs, const float* __restrict__ wsro,
    float* __restrict__ colsum) {
  __shared__ float dist[BN_];
  __shared__ float psh[B_][D_];
  __shared__ float cpsh[B_];
  __shared__ unsigned hist[256];
  __shared__ float rs[256];
  __shared__ int rc[256];
  __shared__ unsigned sprefix;
  __shared__ int skk;
  int tid = threadIdx.x;
  int j = blockIdx.x;
  if (tid < B_ * D_) {
    int b = tid / D_, d = tid % D_;
    psh[b][d] = outputs[(b * N_ + j) * D_ + d];
  }
  if (tid < B_) cpsh[tid] = wsro[WS_PPRE + (tid * N_ + j) * PPRE_STRIDE + 10];
  __syncthreads();
  for (int i = tid; i < BN_; i += 256) {
    int b = i >> 10;  // i / N_
    const float4* pp4 = (const float4*)(wsro + WS_PPRE + i * PPRE_STRIDE);
    float4 a0 = pp4[0], a1 = pp4[1], a2 = pp4[2];
    float dot = a0.x * psh[b][0] + a0.y * psh[b][1] + a0.z * psh[b][2] +
                a0.w * psh[b][3] + a1.x * psh[b][4] + a1.y * psh[b][5] +
                a1.z * psh[b][6] + a1.w * psh[b][7] + a2.x * psh[b][8];
    dist[i] = cpsh[b] + a2.y - 2.0f * dot;  // yAy(col) + qAq(row) - 2 yAq
  }
  __syncthreads();
  float s = select_sum_k<BN_>(dist, K_, hist, rs, rc, &sprefix, &skk);
  if (tid == 0) colsum[j] = s;
}

// ---------------- kernel 5: final deterministic reduce ----------------
__global__ __launch_bounds__(256) void reduce_kernel(
    const float* __restrict__ ws, float* __restrict__ out) {
  __shared__ double sbuf[256];
  __shared__ double tA;
  int tid = threadIdx.x;
  double sa = 0.0, sb = 0.0;
  for (int i = tid; i < N_; i += 256) {
    sa += (double)ws[WS_CS_INTRA + i];
    sb += (double)ws[WS_CS_INTER + i];
  }
  sbuf[tid] = sa;
  __syncthreads();
  for (int off = 128; off > 0; off >>= 1) {
    if (tid < off) sbuf[tid] += sbuf[tid + off];
    __syncthreads();
  }
  if (tid == 0) tA = sbuf[0];
  __syncthreads();
  sbuf[tid] = sb;
  __syncthreads();
  for (int off = 128; off > 0; off >>= 1) {
    if (tid < off) sbuf[tid] += sbuf[tid + off];
    __syncthreads();
  }
  if (tid == 0) {
    double denom = (double)N_ * (double)K_;
    out[0] = (float)(tA / denom - 0.1 * (sbuf[0] / denom));
  }
}

extern "C" void kernel_launch(void* const* d_in, const int* in_sizes, int n_in,
                              void* d_out, int out_size, void* d_ws,
                              size_t ws_size, hipStream_t stream) {
  const float* outputs = (const float*)d_in[0];
  const float* targets = (const float*)d_in[1];
  const void* mask = d_in[2];
  float* ws = (float*)d_ws;

  hipLaunchKernelGGL(stats_kernel, dim3(1), dim3(256), 0, stream, targets, mask, ws);
  hipLaunchKernelGGL(pre_kernel, dim3((BM_ + BN_ + 255) / 256), dim3(256), 0,
                     stream, outputs, targets, mask, ws);
  hipLaunchKernelGGL(intra_kernel, dim3(N_), dim3(256), 0, stream, outputs, ws,
                     ws + WS_CS_INTRA);
  hipLaunchKernelGGL(inter_kernel, dim3(N_), dim3(256), 0, stream, outputs, ws,
                     ws + WS_CS_INTER);
  hipLaunchKernelGGL(reduce_kernel, dim3(1), dim3(256), 0, stream, ws,
                     (float*)d_out);
}

// Round 2
// 223.541 us; speedup vs baseline: 1.5893x; 1.5893x over previous
//
#include <hip/hip_runtime.h>
#include <math.h>

#define B_ 4
#define N_ 1024
#define M_ 2048
#define D_ 9
#define K_ 64
#define BM_ (B_*M_)   // 8192 targets
#define BN_ (B_*N_)   // 4096 preds
#define TPRE_STRIDE 12
#define PPRE_STRIDE 12
#define NPART 32      // stats partial blocks
#define NSTAT 55      // 1 + 9 + 45 accumulators

// workspace layout (in floats)
#define WS_A 0                                   // 81: cov_inv (symmetric)
#define WS_MEAN 81                               // 9
#define WS_TPRE 96                               // 8192*12: [Au(9), uAu, pad, pad]
#define WS_PPRE (WS_TPRE + BM_*TPRE_STRIDE)      // 4096*12: [Aq(9), qAq, yAy, pad]
#define WS_CS_INTRA (WS_PPRE + BN_*PPRE_STRIDE)  // 1024 per-column sums
#define WS_CS_INTER (WS_CS_INTRA + N_)           // 1024
#define WS_PART (WS_CS_INTER + N_)               // 32*56 stats partials

__device__ __forceinline__ unsigned f2key(float f) {
  unsigned b = __float_as_uint(f);
  return (b & 0x80000000u) ? ~b : (b | 0x80000000u);
}
__device__ __forceinline__ float key2f(unsigned k) {
  unsigned b = (k & 0x80000000u) ? (k ^ 0x80000000u) : ~k;
  return __uint_as_float(b);
}

// mask dtype auto-detect from first 8192 bytes (always in-bounds for
// u8/i32/i64 layouts). 0 = u8/bool, 1 = int32, 2 = int64.
__device__ int detect_mask_fmt(const void* mask, int* flags /*shared[2]*/) {
  int tid = threadIdx.x;
  if (tid < 2) flags[tid] = 0;
  __syncthreads();
  const unsigned char* mb = (const unsigned char*)mask;
  int la = 0, lb = 0;
  for (int i = tid; i < BM_; i += 256) {
    unsigned char c = mb[i];
    if (c) { if (i & 3) la = 1; else if ((i & 7) == 4) lb = 1; }
  }
  if (la) atomicOr(&flags[0], 1);
  if (lb) atomicOr(&flags[1], 1);
  __syncthreads();
  return flags[0] ? 0 : (flags[1] ? 1 : 2);
}
__device__ __forceinline__ int mask_at(const void* mask, int fmt, int t) {
  if (fmt == 0) return ((const unsigned char*)mask)[t] != 0;
  if (fmt == 1) return ((const int*)mask)[t] != 0;
  return ((const long long*)mask)[t] != 0LL;
}

// -------- kernel 1a: per-block partial stats (S, Σt, Σ t tᵀ) in f32 --------
__global__ __launch_bounds__(256) void stats_part_kernel(
    const float* __restrict__ targets, const void* __restrict__ mask,
    float* __restrict__ ws) {
  __shared__ int flags[2];
  __shared__ float wpart[4][NSTAT];
  int tid = threadIdx.x;
  int fmt = detect_mask_fmt(mask, flags);
  int t = blockIdx.x * 256 + tid;  // one target per thread (BM_ = 32*256)

  float v[NSTAT];
  float tv[D_];
  int m = mask_at(mask, fmt, t);
  const float* tp = targets + t * D_;
#pragma unroll
  for (int d = 0; d < D_; ++d) tv[d] = m ? tp[d] : 0.f;
  v[0] = m ? 1.f : 0.f;
#pragma unroll
  for (int d = 0; d < D_; ++d) v[1 + d] = tv[d];
  {
    int p = 10;
#pragma unroll
    for (int i = 0; i < D_; ++i)
#pragma unroll
      for (int j = i; j < D_; ++j, ++p) v[p] = tv[i] * tv[j];
  }
  // wave-level butterfly reduce (64 lanes)
#pragma unroll
  for (int off = 32; off > 0; off >>= 1)
#pragma unroll
    for (int p = 0; p < NSTAT; ++p) v[p] += __shfl_down(v[p], off);
  int wave = tid >> 6, lane = tid & 63;
  if (lane == 0)
#pragma unroll
    for (int p = 0; p < NSTAT; ++p) wpart[wave][p] = v[p];
  __syncthreads();
  if (tid < NSTAT) {
    float s = wpart[0][tid] + wpart[1][tid] + wpart[2][tid] + wpart[3][tid];
    ws[WS_PART + blockIdx.x * (NSTAT + 1) + tid] = s;
  }
}

// -------- kernel 1b: combine partials, build cov, invert (f64) --------
__global__ __launch_bounds__(64) void stats_fin_kernel(float* __restrict__ ws) {
  __shared__ double tot[NSTAT];
  int tid = threadIdx.x;
  if (tid < NSTAT) {
    double s = 0.0;
    for (int b = 0; b < NPART; ++b)
      s += (double)ws[WS_PART + b * (NSTAT + 1) + tid];
    tot[tid] = s;
  }
  __syncthreads();
  if (tid == 0) {
    double S = tot[0];
    double mean[D_];
    for (int d = 0; d < D_; ++d) mean[d] = tot[1 + d] / S;
    double Cm[D_][D_], Ai[D_][D_];
    double denom = S - 1.0;
    int p = 10;
    for (int i = 0; i < D_; ++i)
      for (int j = i; j < D_; ++j, ++p) {
        double v = (tot[p] - S * mean[i] * mean[j]) / denom;
        Cm[i][j] = v; Cm[j][i] = v;
      }
    for (int i = 0; i < D_; ++i)
      for (int j = 0; j < D_; ++j) Ai[i][j] = (i == j) ? 1.0 : 0.0;
    // Gauss-Jordan with partial pivoting (f64)
    for (int c = 0; c < D_; ++c) {
      int piv = c; double pv = fabs(Cm[c][c]);
      for (int r = c + 1; r < D_; ++r)
        if (fabs(Cm[r][c]) > pv) { pv = fabs(Cm[r][c]); piv = r; }
      if (piv != c) {
        for (int j = 0; j < D_; ++j) {
          double t1 = Cm[c][j]; Cm[c][j] = Cm[piv][j]; Cm[piv][j] = t1;
          t1 = Ai[c][j]; Ai[c][j] = Ai[piv][j]; Ai[piv][j] = t1;
        }
      }
      double inv = 1.0 / Cm[c][c];
      for (int j = 0; j < D_; ++j) { Cm[c][j] *= inv; Ai[c][j] *= inv; }
      for (int r = 0; r < D_; ++r) {
        if (r == c) continue;
        double f = Cm[r][c];
        if (f != 0.0)
          for (int j = 0; j < D_; ++j) {
            Cm[r][j] -= f * Cm[c][j]; Ai[r][j] -= f * Ai[c][j];
          }
      }
    }
    for (int i = 0; i < D_; ++i)
      for (int j = 0; j < D_; ++j)
        ws[WS_A + i * D_ + j] = (float)(0.5 * (Ai[i][j] + Ai[j][i]));
    for (int d = 0; d < D_; ++d) ws[WS_MEAN + d] = (float)mean[d];
  }
}

// ---------------- kernel 2: precompute factored terms ----------------
__global__ __launch_bounds__(256) void pre_kernel(
    const float* __restrict__ outputs, const float* __restrict__ targets,
    const void* __restrict__ mask, float* __restrict__ ws) {
  __shared__ int flags[2];
  __shared__ float Ash[81];
  __shared__ float msh[D_];
  int tid = threadIdx.x;
  int fmt = detect_mask_fmt(mask, flags);
  if (tid < 81) Ash[tid] = ws[WS_A + tid];
  if (tid < D_) msh[tid] = ws[WS_MEAN + tid];
  __syncthreads();
  int idx = blockIdx.x * 256 + tid;
  if (idx < BM_) {
    // target side: u = t - mean; store Au, uᵀAu (inf if masked out)
    const float* tp = targets + idx * D_;
    float u[D_];
#pragma unroll
    for (int d = 0; d < D_; ++d) u[d] = tp[d] - msh[d];
    float cu = 0.f; float au[D_];
#pragma unroll
    for (int i = 0; i < D_; ++i) {
      float s = 0.f;
#pragma unroll
      for (int j = 0; j < D_; ++j) s += Ash[i * D_ + j] * u[j];
      au[i] = s; cu += u[i] * s;
    }
    if (!mask_at(mask, fmt, idx)) cu = INFINITY;
    float* o = ws + WS_TPRE + idx * TPRE_STRIDE;
#pragma unroll
    for (int d = 0; d < D_; ++d) o[d] = au[d];
    o[9] = cu; o[10] = 0.f; o[11] = 0.f;
  } else if (idx < BM_ + BN_) {
    // pred side: q = y + mean; store Aq, qᵀAq, yᵀAy
    int r = idx - BM_;
    const float* yp = outputs + r * D_;
    float y[D_], q[D_], aq[D_];
#pragma unroll
    for (int d = 0; d < D_; ++d) { y[d] = yp[d]; q[d] = y[d] + msh[d]; }
    float cp = 0.f, cq = 0.f;
#pragma unroll
    for (int i = 0; i < D_; ++i) {
      float sy = 0.f, sq = 0.f;
#pragma unroll
      for (int j = 0; j < D_; ++j) {
        sy += Ash[i * D_ + j] * y[j];
        sq += Ash[i * D_ + j] * q[j];
      }
      cp += y[i] * sy;
      aq[i] = sq; cq += q[i] * sq;
    }
    float* o = ws + WS_PPRE + r * PPRE_STRIDE;
#pragma unroll
    for (int d = 0; d < D_; ++d) o[d] = aq[d];
    o[9] = cq; o[10] = cp; o[11] = 0.f;
  }
}

// ------------- deterministic radix-select: sum of k smallest -------------
template <int V>
__device__ float select_sum_k(const float* vals, int k, unsigned* hist,
                              float* rs, int* rc, unsigned* sprefix, int* skk) {
  int tid = threadIdx.x;
  unsigned prefix = 0;
  int kk = k;
  for (int shift = 24; shift >= 0; shift -= 8) {
    hist[tid] = 0;
    __syncthreads();
    unsigned himask = (shift == 24) ? 0u : (0xFFFFFFFFu << (shift + 8));
    for (int i = tid; i < V; i += 256) {
      unsigned key = f2key(vals[i]);
      if ((key & himask) == prefix)
        atomicAdd(&hist[(key >> shift) & 0xFFu], 1u);
    }
    __syncthreads();
    if (tid == 0) {
      int cum = 0; int bin = 0;
      for (; bin < 255; ++bin) {
        int h = (int)hist[bin];
        if (cum + h >= kk) break;
        cum += h;
      }
      *sprefix = prefix | ((unsigned)bin << shift);
      *skk = kk - cum;
    }
    __syncthreads();
    prefix = *sprefix; kk = *skk;
    __syncthreads();
  }
  unsigned tau = prefix;           // exact key of k-th smallest
  float tauval = key2f(tau);
  float psum = 0.f; int pcnt = 0;
  for (int i = tid; i < V; i += 256) {
    float v = vals[i];
    if (f2key(v) < tau) { psum += v; pcnt++; }
  }
  rs[tid] = psum; rc[tid] = pcnt;
  __syncthreads();
  for (int off = 128; off > 0; off >>= 1) {
    if (tid < off) { rs[tid] += rs[tid + off]; rc[tid] += rc[tid + off]; }
    __syncthreads();
  }
  return rs[0] + (float)(k - rc[0]) * tauval;
}

// ---------------- kernel 3: intra (per-column over 8192 targets) ----------------
__global__ __launch_bounds__(256) void intra_kernel(
    const float* __restrict__ outputs, const float* __restrict__ wsro,
    float* __restrict__ colsum) {
  __shared__ float dist[BM_];
  __shared__ float vsh[B_][D_];
  __shared__ float cvsh[B_];
  __shared__ unsigned hist[256];
  __shared__ float rs[256];
  __shared__ int rc[256];
  __shared__ unsigned sprefix;
  __shared__ int skk;
  int tid = threadIdx.x;
  int n = blockIdx.x;
  if (tid < B_ * D_) {
    int b = tid / D_, d = tid % D_;
    vsh[b][d] = outputs[(b * N_ + n) * D_ + d];
  }
  if (tid < B_) cvsh[tid] = wsro[WS_PPRE + (tid * N_ + n) * PPRE_STRIDE + 10];
  __syncthreads();
  for (int i = tid; i < BM_; i += 256) {
    int b = i >> 11;  // i / M_
    const float4* tp4 = (const float4*)(wsro + WS_TPRE + i * TPRE_STRIDE);
    float4 a0 = tp4[0], a1 = tp4[1], a2 = tp4[2];
    float dot = a0.x * vsh[b][0] + a0.y * vsh[b][1] + a0.z * vsh[b][2] +
                a0.w * vsh[b][3] + a1.x * vsh[b][4] + a1.y * vsh[b][5] +
                a1.z * vsh[b][6] + a1.w * vsh[b][7] + a2.x * vsh[b][8];
    dist[i] = a2.y + cvsh[b] - 2.0f * dot;  // uAu + yAy - 2 uAy
  }
  __syncthreads();
  float s = select_sum_k<BM_>(dist, K_, hist, rs, rc, &sprefix, &skk);
  if (tid == 0) colsum[n] = s;
}

// ---------------- kernel 4: inter (per-column over 4096 preds) ----------------
__global__ __launch_bounds__(256) void inter_kernel(
    const float* __restrict__ outputs, const float* __restrict__ wsro,
    float* __restrict__ colsum) {
  __shared__ float dist[BN_];
  __shared__ float psh[B_][D_];
  __shared__ float cpsh[B_];
  __shared__ unsigned hist[256];
  __shared__ float rs[256];
  __shared__ int rc[256];
  __shared__ unsigned sprefix;
  __shared__ int skk;
  int tid = threadIdx.x;
  int j = blockIdx.x;
  if (tid < B_ * D_) {
    int b = tid / D_, d = tid % D_;
    psh[b][d] = outputs[(b * N_ + j) * D_ + d];
  }
  if (tid < B_) cpsh[tid] = wsro[WS_PPRE + (tid * N_ + j) * PPRE_STRIDE + 10];
  __syncthreads();
  for (int i = tid; i < BN_; i += 256) {
    int b = i >> 10;  // i / N_
    const float4* pp4 = (const float4*)(wsro + WS_PPRE + i * PPRE_STRIDE);
    float4 a0 = pp4[0], a1 = pp4[1], a2 = pp4[2];
    float dot = a0.x * psh[b][0] + a0.y * psh[b][1] + a0.z * psh[b][2] +
                a0.w * psh[b][3] + a1.x * psh[b][4] + a1.y * psh[b][5] +
                a1.z * psh[b][6] + a1.w * psh[b][7] + a2.x * psh[b][8];
    dist[i] = cpsh[b] + a2.y - 2.0f * dot;  // yAy(col) + qAq(row) - 2 yAq
  }
  __syncthreads();
  float s = select_sum_k<BN_>(dist, K_, hist, rs, rc, &sprefix, &skk);
  if (tid == 0) colsum[j] = s;
}

// ---------------- kernel 5: final deterministic reduce ----------------
__global__ __launch_bounds__(256) void reduce_kernel(
    const float* __restrict__ ws, float* __restrict__ out) {
  __shared__ double sbuf[256];
  __shared__ double tA;
  int tid = threadIdx.x;
  double sa = 0.0, sb = 0.0;
  for (int i = tid; i < N_; i += 256) {
    sa += (double)ws[WS_CS_INTRA + i];
    sb += (double)ws[WS_CS_INTER + i];
  }
  sbuf[tid] = sa;
  __syncthreads();
  for (int off = 128; off > 0; off >>= 1) {
    if (tid < off) sbuf[tid] += sbuf[tid + off];
    __syncthreads();
  }
  if (tid == 0) tA = sbuf[0];
  __syncthreads();
  sbuf[tid] = sb;
  __syncthreads();
  for (int off = 128; off > 0; off >>= 1) {
    if (tid < off) sbuf[tid] += sbuf[tid + off];
    __syncthreads();
  }
  if (tid == 0) {
    double denom = (double)N_ * (double)K_;
    out[0] = (float)(tA / denom - 0.1 * (sbuf[0] / denom));
  }
}

extern "C" void kernel_launch(void* const* d_in, const int* in_sizes, int n_in,
                              void* d_out, int out_size, void* d_ws,
                              size_t ws_size, hipStream_t stream) {
  const float* outputs = (const float*)d_in[0];
  const float* targets = (const float*)d_in[1];
  const void* mask = d_in[2];
  float* ws = (float*)d_ws;

  hipLaunchKernelGGL(stats_part_kernel, dim3(NPART), dim3(256), 0, stream,
                     targets, mask, ws);
  hipLaunchKernelGGL(stats_fin_kernel, dim3(1), dim3(64), 0, stream, ws);
  hipLaunchKernelGGL(pre_kernel, dim3((BM_ + BN_ + 255) / 256), dim3(256), 0,
                     stream, outputs, targets, mask, ws);
  hipLaunchKernelGGL(intra_kernel, dim3(N_), dim3(256), 0, stream, outputs, ws,
                     ws + WS_CS_INTRA);
  hipLaunchKernelGGL(inter_kernel, dim3(N_), dim3(256), 0, stream, outputs, ws,
                     ws + WS_CS_INTER);
  hipLaunchKernelGGL(reduce_kernel, dim3(1), dim3(256), 0, stream, ws,
                     (float*)d_out);
}

// Round 3
// 167.801 us; speedup vs baseline: 2.1172x; 1.3322x over previous
//
#include <hip/hip_runtime.h>
#include <math.h>

#define B_ 4
#define N_ 1024
#define M_ 2048
#define D_ 9
#define K_ 64
#define BM_ (B_*M_)   // 8192 targets
#define BN_ (B_*N_)   // 4096 preds
#define TPRE_STRIDE 12
#define PPRE_STRIDE 12
#define NPART 32      // stats partial blocks
#define NSTAT 55      // 1 + 9 + 45 accumulators
#define TSEL 512      // select kernel block size

// workspace layout (in floats)
#define WS_A 0                                   // 81: cov_inv (symmetric)
#define WS_MEAN 81                               // 9
#define WS_TPRE 96                               // 8192*12: [Au(9), uAu, pad, pad]
#define WS_PPRE (WS_TPRE + BM_*TPRE_STRIDE)      // 4096*12: [Aq(9), qAq, yAy, pad]
#define WS_CS_INTRA (WS_PPRE + BN_*PPRE_STRIDE)  // 1024 per-column sums
#define WS_CS_INTER (WS_CS_INTRA + N_)           // 1024
#define WS_PART (WS_CS_INTER + N_)               // 32*56 stats partials

__device__ __forceinline__ unsigned f2key(float f) {
  unsigned b = __float_as_uint(f);
  return (b & 0x80000000u) ? ~b : (b | 0x80000000u);
}
__device__ __forceinline__ float key2f(unsigned k) {
  unsigned b = (k & 0x80000000u) ? (k ^ 0x80000000u) : ~k;
  return __uint_as_float(b);
}

// mask dtype auto-detect from first 8192 bytes (always in-bounds for
// u8/i32/i64 layouts). 0 = u8/bool, 1 = int32, 2 = int64.
__device__ int detect_mask_fmt(const void* mask, int* flags /*shared[2]*/) {
  int tid = threadIdx.x;
  if (tid < 2) flags[tid] = 0;
  __syncthreads();
  const unsigned char* mb = (const unsigned char*)mask;
  int la = 0, lb = 0;
  for (int i = tid; i < BM_; i += blockDim.x) {
    unsigned char c = mb[i];
    if (c) { if (i & 3) la = 1; else if ((i & 7) == 4) lb = 1; }
  }
  if (la) atomicOr(&flags[0], 1);
  if (lb) atomicOr(&flags[1], 1);
  __syncthreads();
  return flags[0] ? 0 : (flags[1] ? 1 : 2);
}
__device__ __forceinline__ int mask_at(const void* mask, int fmt, int t) {
  if (fmt == 0) return ((const unsigned char*)mask)[t] != 0;
  if (fmt == 1) return ((const int*)mask)[t] != 0;
  return ((const long long*)mask)[t] != 0LL;
}

// -------- kernel 1a: per-block partial stats (S, Σt, Σ t tᵀ) in f32 --------
__global__ __launch_bounds__(256) void stats_part_kernel(
    const float* __restrict__ targets, const void* __restrict__ mask,
    float* __restrict__ ws) {
  __shared__ int flags[2];
  __shared__ float wpart[4][NSTAT];
  int tid = threadIdx.x;
  int fmt = detect_mask_fmt(mask, flags);
  int t = blockIdx.x * 256 + tid;  // one target per thread (BM_ = 32*256)

  float v[NSTAT];
  float tv[D_];
  int m = mask_at(mask, fmt, t);
  const float* tp = targets + t * D_;
#pragma unroll
  for (int d = 0; d < D_; ++d) tv[d] = m ? tp[d] : 0.f;
  v[0] = m ? 1.f : 0.f;
#pragma unroll
  for (int d = 0; d < D_; ++d) v[1 + d] = tv[d];
  {
    int p = 10;
#pragma unroll
    for (int i = 0; i < D_; ++i)
#pragma unroll
      for (int j = i; j < D_; ++j, ++p) v[p] = tv[i] * tv[j];
  }
#pragma unroll
  for (int off = 32; off > 0; off >>= 1)
#pragma unroll
    for (int p = 0; p < NSTAT; ++p) v[p] += __shfl_down(v[p], off);
  int wave = tid >> 6, lane = tid & 63;
  if (lane == 0)
#pragma unroll
    for (int p = 0; p < NSTAT; ++p) wpart[wave][p] = v[p];
  __syncthreads();
  if (tid < NSTAT) {
    float s = wpart[0][tid] + wpart[1][tid] + wpart[2][tid] + wpart[3][tid];
    ws[WS_PART + blockIdx.x * (NSTAT + 1) + tid] = s;
  }
}

// -------- kernel 1b: combine partials, build cov, invert (f64) --------
__global__ __launch_bounds__(64) void stats_fin_kernel(float* __restrict__ ws) {
  __shared__ double tot[NSTAT];
  int tid = threadIdx.x;
  if (tid < NSTAT) {
    double s = 0.0;
    for (int b = 0; b < NPART; ++b)
      s += (double)ws[WS_PART + b * (NSTAT + 1) + tid];
    tot[tid] = s;
  }
  __syncthreads();
  if (tid == 0) {
    double S = tot[0];
    double mean[D_];
    for (int d = 0; d < D_; ++d) mean[d] = tot[1 + d] / S;
    double Cm[D_][D_], Ai[D_][D_];
    double denom = S - 1.0;
    int p = 10;
    for (int i = 0; i < D_; ++i)
      for (int j = i; j < D_; ++j, ++p) {
        double v = (tot[p] - S * mean[i] * mean[j]) / denom;
        Cm[i][j] = v; Cm[j][i] = v;
      }
    for (int i = 0; i < D_; ++i)
      for (int j = 0; j < D_; ++j) Ai[i][j] = (i == j) ? 1.0 : 0.0;
    for (int c = 0; c < D_; ++c) {
      int piv = c; double pv = fabs(Cm[c][c]);
      for (int r = c + 1; r < D_; ++r)
        if (fabs(Cm[r][c]) > pv) { pv = fabs(Cm[r][c]); piv = r; }
      if (piv != c) {
        for (int j = 0; j < D_; ++j) {
          double t1 = Cm[c][j]; Cm[c][j] = Cm[piv][j]; Cm[piv][j] = t1;
          t1 = Ai[c][j]; Ai[c][j] = Ai[piv][j]; Ai[piv][j] = t1;
        }
      }
      double inv = 1.0 / Cm[c][c];
      for (int j = 0; j < D_; ++j) { Cm[c][j] *= inv; Ai[c][j] *= inv; }
      for (int r = 0; r < D_; ++r) {
        if (r == c) continue;
        double f = Cm[r][c];
        if (f != 0.0)
          for (int j = 0; j < D_; ++j) {
            Cm[r][j] -= f * Cm[c][j]; Ai[r][j] -= f * Ai[c][j];
          }
      }
    }
    for (int i = 0; i < D_; ++i)
      for (int j = 0; j < D_; ++j)
        ws[WS_A + i * D_ + j] = (float)(0.5 * (Ai[i][j] + Ai[j][i]));
    for (int d = 0; d < D_; ++d) ws[WS_MEAN + d] = (float)mean[d];
  }
}

// ---------------- kernel 2: precompute factored terms ----------------
__global__ __launch_bounds__(256) void pre_kernel(
    const float* __restrict__ outputs, const float* __restrict__ targets,
    const void* __restrict__ mask, float* __restrict__ ws) {
  __shared__ int flags[2];
  __shared__ float Ash[81];
  __shared__ float msh[D_];
  int tid = threadIdx.x;
  int fmt = detect_mask_fmt(mask, flags);
  if (tid < 81) Ash[tid] = ws[WS_A + tid];
  if (tid < D_) msh[tid] = ws[WS_MEAN + tid];
  __syncthreads();
  int idx = blockIdx.x * 256 + tid;
  if (idx < BM_) {
    const float* tp = targets + idx * D_;
    float u[D_];
#pragma unroll
    for (int d = 0; d < D_; ++d) u[d] = tp[d] - msh[d];
    float cu = 0.f; float au[D_];
#pragma unroll
    for (int i = 0; i < D_; ++i) {
      float s = 0.f;
#pragma unroll
      for (int j = 0; j < D_; ++j) s += Ash[i * D_ + j] * u[j];
      au[i] = s; cu += u[i] * s;
    }
    if (!mask_at(mask, fmt, idx)) cu = INFINITY;
    float* o = ws + WS_TPRE + idx * TPRE_STRIDE;
#pragma unroll
    for (int d = 0; d < D_; ++d) o[d] = au[d];
    o[9] = cu; o[10] = 0.f; o[11] = 0.f;
  } else if (idx < BM_ + BN_) {
    int r = idx - BM_;
    const float* yp = outputs + r * D_;
    float y[D_], q[D_], aq[D_];
#pragma unroll
    for (int d = 0; d < D_; ++d) { y[d] = yp[d]; q[d] = y[d] + msh[d]; }
    float cp = 0.f, cq = 0.f;
#pragma unroll
    for (int i = 0; i < D_; ++i) {
      float sy = 0.f, sq = 0.f;
#pragma unroll
      for (int j = 0; j < D_; ++j) {
        sy += Ash[i * D_ + j] * y[j];
        sq += Ash[i * D_ + j] * q[j];
      }
      cp += y[i] * sy;
      aq[i] = sq; cq += q[i] * sq;
    }
    float* o = ws + WS_PPRE + r * PPRE_STRIDE;
#pragma unroll
    for (int d = 0; d < D_; ++d) o[d] = aq[d];
    o[9] = cq; o[10] = cp; o[11] = 0.f;
  }
}

// ------- register-key bisection select: sum of K_ smallest, deterministic -------
// keys live in VGPRs; per step: unrolled register count + wave shfl-reduce +
// one double-buffered LDS exchange (ONE barrier); every thread redundantly
// combines the 8 wave partials so lo/hi stay block-uniform with no serial phase.
template <int V, int SHIFT>
__device__ __forceinline__ float sel_sum(const float* __restrict__ pre,
                                         const float (*vsh)[12],
                                         const float* cvsh,
                                         int (*wpart)[8],
                                         float* fpart, int* cpart) {
  constexpr int PER = V / TSEL;
  int tid = threadIdx.x;
  int wave = tid >> 6, lane = tid & 63;
  unsigned key[PER];
#pragma unroll
  for (int j = 0; j < PER; ++j) {
    int i = tid + TSEL * j;
    int b = i >> SHIFT;
    const float4* p4 = (const float4*)(pre + i * 12);
    float4 a0 = p4[0], a1 = p4[1], a2 = p4[2];
    float dot = a0.x * vsh[b][0] + a0.y * vsh[b][1] + a0.z * vsh[b][2] +
                a0.w * vsh[b][3] + a1.x * vsh[b][4] + a1.y * vsh[b][5] +
                a1.z * vsh[b][6] + a1.w * vsh[b][7] + a2.x * vsh[b][8];
    key[j] = f2key(a2.y + cvsh[b] - 2.0f * dot);
  }
  // bisect for T = key of K_-th smallest. T is solidly positive (distances);
  // lo starts at key(+0.0). count(<=hi0) == V >= K_ always.
  unsigned lo = 0x80000000u, hi = 0xFF800000u;
#pragma unroll 1
  for (int step = 0; step < 32; ++step) {
    if (lo >= hi) break;  // block-uniform
    unsigned mid = lo + ((hi - lo) >> 1);
    int cnt = 0;
#pragma unroll
    for (int j = 0; j < PER; ++j) cnt += (key[j] <= mid) ? 1 : 0;
#pragma unroll
    for (int off = 32; off > 0; off >>= 1) cnt += __shfl_down(cnt, off);
    if (lane == 0) wpart[step & 1][wave] = cnt;
    __syncthreads();
    int tot = 0;
#pragma unroll
    for (int w = 0; w < TSEL / 64; ++w) tot += wpart[step & 1][w];
    if (tot >= K_) hi = mid; else lo = mid + 1;
  }
  unsigned T = lo;
  float tval = key2f(T);
  float s = 0.f; int c = 0;
#pragma unroll
  for (int j = 0; j < PER; ++j)
    if (key[j] < T) { s += key2f(key[j]); c++; }
#pragma unroll
  for (int off = 32; off > 0; off >>= 1) {
    s += __shfl_down(s, off);
    c += __shfl_down(c, off);
  }
  __syncthreads();  // wpart reads done before reusing LDS region semantics
  if (lane == 0) { fpart[wave] = s; cpart[wave] = c; }
  __syncthreads();
  float fs = 0.f; int fc = 0;
#pragma unroll
  for (int w = 0; w < TSEL / 64; ++w) { fs += fpart[w]; fc += cpart[w]; }
  return fs + (float)(K_ - fc) * tval;
}

// ------- kernel 3: fused intra+inter select (blocks 0..N-1 intra, N..2N-1 inter) -------
__global__ __launch_bounds__(TSEL, 4) void select_kernel(
    const float* __restrict__ outputs, const float* __restrict__ wsro,
    float* __restrict__ ws) {
  __shared__ float vsh[B_][12];
  __shared__ float cvsh[B_];
  __shared__ int wpart[2][8];
  __shared__ float fpart[8];
  __shared__ int cpart[8];
  int tid = threadIdx.x;
  int bid = blockIdx.x;
  int is_intra = bid < N_;
  int col = is_intra ? bid : bid - N_;
  if (tid < B_ * D_) {
    int b = tid / D_, d = tid % D_;
    vsh[b][d] = outputs[(b * N_ + col) * D_ + d];
  }
  if (tid < B_) cvsh[tid] = wsro[WS_PPRE + (tid * N_ + col) * PPRE_STRIDE + 10];
  __syncthreads();
  float s;
  if (is_intra)
    s = sel_sum<BM_, 11>(wsro + WS_TPRE, vsh, cvsh, wpart, fpart, cpart);
  else
    s = sel_sum<BN_, 10>(wsro + WS_PPRE, vsh, cvsh, wpart, fpart, cpart);
  if (tid == 0)
    ws[(is_intra ? WS_CS_INTRA : WS_CS_INTER) + col] = s;
}

// ---------------- kernel 4: final deterministic reduce ----------------
__global__ __launch_bounds__(256) void reduce_kernel(
    const float* __restrict__ ws, float* __restrict__ out) {
  __shared__ double sbuf[256];
  __shared__ double tA;
  int tid = threadIdx.x;
  double sa = 0.0, sb = 0.0;
  for (int i = tid; i < N_; i += 256) {
    sa += (double)ws[WS_CS_INTRA + i];
    sb += (double)ws[WS_CS_INTER + i];
  }
  sbuf[tid] = sa;
  __syncthreads();
  for (int off = 128; off > 0; off >>= 1) {
    if (tid < off) sbuf[tid] += sbuf[tid + off];
    __syncthreads();
  }
  if (tid == 0) tA = sbuf[0];
  __syncthreads();
  sbuf[tid] = sb;
  __syncthreads();
  for (int off = 128; off > 0; off >>= 1) {
    if (tid < off) sbuf[tid] += sbuf[tid + off];
    __syncthreads();
  }
  if (tid == 0) {
    double denom = (double)N_ * (double)K_;
    out[0] = (float)(tA / denom - 0.1 * (sbuf[0] / denom));
  }
}

extern "C" void kernel_launch(void* const* d_in, const int* in_sizes, int n_in,
                              void* d_out, int out_size, void* d_ws,
                              size_t ws_size, hipStream_t stream) {
  const float* outputs = (const float*)d_in[0];
  const float* targets = (const float*)d_in[1];
  const void* mask = d_in[2];
  float* ws = (float*)d_ws;

  hipLaunchKernelGGL(stats_part_kernel, dim3(NPART), dim3(256), 0, stream,
                     targets, mask, ws);
  hipLaunchKernelGGL(stats_fin_kernel, dim3(1), dim3(64), 0, stream, ws);
  hipLaunchKernelGGL(pre_kernel, dim3((BM_ + BN_ + 255) / 256), dim3(256), 0,
                     stream, outputs, targets, mask, ws);
  hipLaunchKernelGGL(select_kernel, dim3(2 * N_), dim3(TSEL), 0, stream,
                     outputs, ws, ws);
  hipLaunchKernelGGL(reduce_kernel, dim3(1), dim3(256), 0, stream, ws,
                     (float*)d_out);
}

// Round 4
// 126.085 us; speedup vs baseline: 2.8177x; 1.3309x over previous
//
#include <hip/hip_runtime.h>
#include <math.h>

#define B_ 4
#define N_ 1024
#define M_ 2048
#define D_ 9
#define K_ 64
#define BM_ (B_*M_)   // 8192 targets
#define BN_ (B_*N_)   // 4096 preds
#define TPRE_STRIDE 12
#define PPRE_STRIDE 12
#define NPART 32      // stats partial blocks
#define NSTAT 55      // 1 + 9 + 45 accumulators
#define TSEL 512      // select kernel block size

// workspace layout (in floats)
#define WS_A 0                                   // 81: cov_inv (symmetric)
#define WS_MEAN 81                               // 9
#define WS_TPRE 96                               // 8192*12: [Au(9), uAu, pad, pad]
#define WS_PPRE (WS_TPRE + BM_*TPRE_STRIDE)      // 4096*12: [Aq(9), qAq, yAy, pad]
#define WS_CS_INTRA (WS_PPRE + BN_*PPRE_STRIDE)  // 1024 per-column sums
#define WS_CS_INTER (WS_CS_INTRA + N_)           // 1024
#define WS_PART (WS_CS_INTER + N_)               // 32*56 stats partials

__device__ __forceinline__ unsigned f2key(float f) {
  unsigned b = __float_as_uint(f);
  return (b & 0x80000000u) ? ~b : (b | 0x80000000u);
}
__device__ __forceinline__ float key2f(unsigned k) {
  unsigned b = (k & 0x80000000u) ? (k ^ 0x80000000u) : ~k;
  return __uint_as_float(b);
}

// mask dtype auto-detect from first 8192 bytes (always in-bounds for
// u8/i32/i64 layouts). 0 = u8/bool, 1 = int32, 2 = int64.
__device__ int detect_mask_fmt(const void* mask, int* flags /*shared[2]*/) {
  int tid = threadIdx.x;
  if (tid < 2) flags[tid] = 0;
  __syncthreads();
  const unsigned char* mb = (const unsigned char*)mask;
  int la = 0, lb = 0;
  for (int i = tid; i < BM_; i += blockDim.x) {
    unsigned char c = mb[i];
    if (c) { if (i & 3) la = 1; else if ((i & 7) == 4) lb = 1; }
  }
  if (la) atomicOr(&flags[0], 1);
  if (lb) atomicOr(&flags[1], 1);
  __syncthreads();
  return flags[0] ? 0 : (flags[1] ? 1 : 2);
}
__device__ __forceinline__ int mask_at(const void* mask, int fmt, int t) {
  if (fmt == 0) return ((const unsigned char*)mask)[t] != 0;
  if (fmt == 1) return ((const int*)mask)[t] != 0;
  return ((const long long*)mask)[t] != 0LL;
}

// -------- kernel 1a: per-block partial stats (S, Σt, Σ t tᵀ) in f32 --------
__global__ __launch_bounds__(256) void stats_part_kernel(
    const float* __restrict__ targets, const void* __restrict__ mask,
    float* __restrict__ ws) {
  __shared__ int flags[2];
  __shared__ float wpart[4][NSTAT];
  int tid = threadIdx.x;
  int fmt = detect_mask_fmt(mask, flags);
  int t = blockIdx.x * 256 + tid;  // one target per thread (BM_ = 32*256)

  float v[NSTAT];
  float tv[D_];
  int m = mask_at(mask, fmt, t);
  const float* tp = targets + t * D_;
#pragma unroll
  for (int d = 0; d < D_; ++d) tv[d] = m ? tp[d] : 0.f;
  v[0] = m ? 1.f : 0.f;
#pragma unroll
  for (int d = 0; d < D_; ++d) v[1 + d] = tv[d];
  {
    int p = 10;
#pragma unroll
    for (int i = 0; i < D_; ++i)
#pragma unroll
      for (int j = i; j < D_; ++j, ++p) v[p] = tv[i] * tv[j];
  }
#pragma unroll
  for (int off = 32; off > 0; off >>= 1)
#pragma unroll
    for (int p = 0; p < NSTAT; ++p) v[p] += __shfl_down(v[p], off);
  int wave = tid >> 6, lane = tid & 63;
  if (lane == 0)
#pragma unroll
    for (int p = 0; p < NSTAT; ++p) wpart[wave][p] = v[p];
  __syncthreads();
  if (tid < NSTAT) {
    float s = wpart[0][tid] + wpart[1][tid] + wpart[2][tid] + wpart[3][tid];
    ws[WS_PART + blockIdx.x * (NSTAT + 1) + tid] = s;
  }
}

// -------- kernel 1b: combine partials; lane-parallel f32 Gauss-Jordan --------
// Covariance is SPD (cond ~1 for standard-normal targets) -> no pivoting.
// Lanes 0..8 own columns of C, lanes 9..17 own columns of the identity/inverse.
__global__ __launch_bounds__(64) void stats_fin_kernel(float* __restrict__ ws) {
  __shared__ float tot[NSTAT];
  __shared__ float Atmp[9][9];
  int lane = threadIdx.x;
  if (lane < NSTAT) {
    double s = 0.0;
    for (int b = 0; b < NPART; ++b)
      s += (double)ws[WS_PART + b * (NSTAT + 1) + lane];
    tot[lane] = (float)s;
  }
  __syncthreads();
  float S = tot[0];
  float col[9];
  int j = lane - 9;
  if (lane < 9) {
    float mj = tot[1 + lane] / S;
#pragma unroll
    for (int r = 0; r < 9; ++r) {
      float mr = tot[1 + r] / S;
      int i0 = r < lane ? r : lane;
      int j0 = r < lane ? lane : r;
      int p = i0 * 9 - (i0 * (i0 - 1)) / 2 + (j0 - i0);
      col[r] = (tot[10 + p] - S * mr * mj) / (S - 1.0f);
    }
  } else {
#pragma unroll
    for (int r = 0; r < 9; ++r) col[r] = (r == j) ? 1.f : 0.f;
  }
#pragma unroll
  for (int c = 0; c < 9; ++c) {
    float pv = __shfl(col[c], c);
    float inv = 1.f / pv;
    col[c] *= inv;  // normalize row c (this lane's element of row c)
    float f[9];
#pragma unroll
    for (int r = 0; r < 9; ++r) f[r] = __shfl(col[r], c);  // column c
#pragma unroll
    for (int r = 0; r < 9; ++r)
      if (r != c) col[r] -= f[r] * col[c];
  }
  if (lane >= 9 && lane < 18) {
#pragma unroll
    for (int r = 0; r < 9; ++r) Atmp[r][j] = col[r];
  }
  __syncthreads();
  if (lane < 9) ws[WS_MEAN + lane] = tot[1 + lane] / S;
  for (int idx = lane; idx < 81; idx += 64) {
    int i0 = idx / 9, j0 = idx % 9;
    ws[WS_A + idx] = 0.5f * (Atmp[i0][j0] + Atmp[j0][i0]);
  }
}

// ---------------- kernel 2: precompute factored terms ----------------
__global__ __launch_bounds__(256) void pre_kernel(
    const float* __restrict__ outputs, const float* __restrict__ targets,
    const void* __restrict__ mask, float* __restrict__ ws) {
  __shared__ int flags[2];
  __shared__ float Ash[81];
  __shared__ float msh[D_];
  int tid = threadIdx.x;
  int fmt = detect_mask_fmt(mask, flags);
  if (tid < 81) Ash[tid] = ws[WS_A + tid];
  if (tid < D_) msh[tid] = ws[WS_MEAN + tid];
  __syncthreads();
  int idx = blockIdx.x * 256 + tid;
  if (idx < BM_) {
    const float* tp = targets + idx * D_;
    float u[D_];
#pragma unroll
    for (int d = 0; d < D_; ++d) u[d] = tp[d] - msh[d];
    float cu = 0.f; float au[D_];
#pragma unroll
    for (int i = 0; i < D_; ++i) {
      float s = 0.f;
#pragma unroll
      for (int j = 0; j < D_; ++j) s += Ash[i * D_ + j] * u[j];
      au[i] = s; cu += u[i] * s;
    }
    if (!mask_at(mask, fmt, idx)) cu = INFINITY;
    float* o = ws + WS_TPRE + idx * TPRE_STRIDE;
#pragma unroll
    for (int d = 0; d < D_; ++d) o[d] = au[d];
    o[9] = cu; o[10] = 0.f; o[11] = 0.f;
  } else if (idx < BM_ + BN_) {
    int r = idx - BM_;
    const float* yp = outputs + r * D_;
    float y[D_], q[D_], aq[D_];
#pragma unroll
    for (int d = 0; d < D_; ++d) { y[d] = yp[d]; q[d] = y[d] + msh[d]; }
    float cp = 0.f, cq = 0.f;
#pragma unroll
    for (int i = 0; i < D_; ++i) {
      float sy = 0.f, sq = 0.f;
#pragma unroll
      for (int j = 0; j < D_; ++j) {
        sy += Ash[i * D_ + j] * y[j];
        sq += Ash[i * D_ + j] * q[j];
      }
      cp += y[i] * sy;
      aq[i] = sq; cq += q[i] * sq;
    }
    float* o = ws + WS_PPRE + r * PPRE_STRIDE;
#pragma unroll
    for (int d = 0; d < D_; ++d) o[d] = aq[d];
    o[9] = cq; o[10] = cp; o[11] = 0.f;
  }
}

// ---- wave-uniform bisection for the exact K_-th smallest key; ballot-count,
// ---- zero barriers, zero shfl chains in the loop. Returns T (an existing key).
template <int PER>
__device__ __forceinline__ unsigned bisect64(const unsigned* key) {
  unsigned kmin = 0xFFFFFFFFu, kmax = 0u;
#pragma unroll
  for (int j = 0; j < PER; ++j) {
    kmin = key[j] < kmin ? key[j] : kmin;
    kmax = key[j] > kmax ? key[j] : kmax;
  }
#pragma unroll
  for (int off = 32; off > 0; off >>= 1) {
    unsigned a = (unsigned)__shfl_xor((int)kmin, off);
    unsigned b = (unsigned)__shfl_xor((int)kmax, off);
    kmin = a < kmin ? a : kmin;
    kmax = b > kmax ? b : kmax;
  }
  unsigned lo = kmin, hi = kmax;
  while (lo < hi) {  // wave-uniform
    unsigned mid = lo + ((hi - lo) >> 1);
    int cnt = 0;
#pragma unroll
    for (int j = 0; j < PER; ++j) cnt += __popcll(__ballot(key[j] <= mid));
    if (cnt >= K_) hi = mid; else lo = mid + 1;
  }
  return lo;
}

// ---- per-wave exact top-64 multiset -> 64-slot LDS region (values < T
// ---- compacted via ballot prefix; padded with copies of T).
template <int PER>
__device__ __forceinline__ void wave_top64(const unsigned* key,
                                           float* __restrict__ candw,
                                           int lane) {
  unsigned T = bisect64<PER>(key);
  unsigned long long lmask = (1ull << lane) - 1ull;
  int nlt = 0;
#pragma unroll
  for (int j = 0; j < PER; ++j) {
    bool p = key[j] < T;
    unsigned long long m = __ballot(p);
    if (p) candw[nlt + __popcll(m & lmask)] = key2f(key[j]);
    nlt += __popcll(m);
  }
  float tv = key2f(T);
  for (int i = nlt + lane; i < K_; i += 64) candw[i] = tv;
}

// ---- exact sum of 64 smallest among 512 candidates (one wave) ----
__device__ __forceinline__ float final_sum64(const float* __restrict__ cand,
                                             int lane) {
  float v[8]; unsigned k8[8];
#pragma unroll
  for (int j = 0; j < 8; ++j) {
    v[j] = cand[j * 64 + lane];
    k8[j] = f2key(v[j]);
  }
  unsigned T = bisect64<8>(k8);
  float s = 0.f; int c = 0;
#pragma unroll
  for (int j = 0; j < 8; ++j)
    if (k8[j] < T) { s += v[j]; c++; }
#pragma unroll
  for (int off = 32; off > 0; off >>= 1) {
    s += __shfl_down(s, off);
    c += __shfl_down(c, off);
  }
  return s + (float)(K_ - c) * key2f(T);  // valid on lane 0
}

// ------- kernel 3: fused intra+inter select, 2 columns per block -------
// blocks 0..511: intra cols (2b, 2b+1); blocks 512..1023: inter cols.
__global__ __launch_bounds__(TSEL) void select_kernel(
    const float* __restrict__ outputs, const float* __restrict__ wsro,
    float* __restrict__ ws) {
  __shared__ float vsh[2][B_][12];
  __shared__ float cvsh[2][B_];
  __shared__ float cand[2][TSEL];
  int tid = threadIdx.x, wave = tid >> 6, lane = tid & 63;
  int bid = blockIdx.x;
  int is_intra = bid < (N_ / 2);
  int c0 = (is_intra ? bid : bid - N_ / 2) * 2;
  if (tid < 72) {
    int c = tid / 36, rem = tid % 36, b = rem / 9, d = rem % 9;
    vsh[c][b][d] = outputs[(b * N_ + c0 + c) * D_ + d];
  }
  if (tid < 8) {
    int c = tid >> 2, b = tid & 3;
    cvsh[c][b] = wsro[WS_PPRE + (b * N_ + c0 + c) * PPRE_STRIDE + 10];
  }
  __syncthreads();
  if (is_intra) {
    constexpr int PER = BM_ / TSEL;  // 16
    unsigned kA[PER], kB[PER];
    const float* pre = wsro + WS_TPRE;
#pragma unroll
    for (int j = 0; j < PER; ++j) {
      int i = tid + TSEL * j;
      int b = i >> 11;
      const float4* p4 = (const float4*)(pre + i * 12);
      float4 a0 = p4[0], a1 = p4[1], a2 = p4[2];
      float dA = a0.x * vsh[0][b][0] + a0.y * vsh[0][b][1] +
                 a0.z * vsh[0][b][2] + a0.w * vsh[0][b][3] +
                 a1.x * vsh[0][b][4] + a1.y * vsh[0][b][5] +
                 a1.z * vsh[0][b][6] + a1.w * vsh[0][b][7] +
                 a2.x * vsh[0][b][8];
      float dB = a0.x * vsh[1][b][0] + a0.y * vsh[1][b][1] +
                 a0.z * vsh[1][b][2] + a0.w * vsh[1][b][3] +
                 a1.x * vsh[1][b][4] + a1.y * vsh[1][b][5] +
                 a1.z * vsh[1][b][6] + a1.w * vsh[1][b][7] +
                 a2.x * vsh[1][b][8];
      kA[j] = f2key(a2.y + cvsh[0][b] - 2.0f * dA);
      kB[j] = f2key(a2.y + cvsh[1][b] - 2.0f * dB);
    }
    wave_top64<PER>(kA, &cand[0][wave * 64], lane);
    wave_top64<PER>(kB, &cand[1][wave * 64], lane);
  } else {
    constexpr int PER = BN_ / TSEL;  // 8
    unsigned kA[PER], kB[PER];
    const float* pre = wsro + WS_PPRE;
#pragma unroll
    for (int j = 0; j < PER; ++j) {
      int i = tid + TSEL * j;
      int b = i >> 10;
      const float4* p4 = (const float4*)(pre + i * 12);
      float4 a0 = p4[0], a1 = p4[1], a2 = p4[2];
      float dA = a0.x * vsh[0][b][0] + a0.y * vsh[0][b][1] +
                 a0.z * vsh[0][b][2] + a0.w * vsh[0][b][3] +
                 a1.x * vsh[0][b][4] + a1.y * vsh[0][b][5] +
                 a1.z * vsh[0][b][6] + a1.w * vsh[0][b][7] +
                 a2.x * vsh[0][b][8];
      float dB = a0.x * vsh[1][b][0] + a0.y * vsh[1][b][1] +
                 a0.z * vsh[1][b][2] + a0.w * vsh[1][b][3] +
                 a1.x * vsh[1][b][4] + a1.y * vsh[1][b][5] +
                 a1.z * vsh[1][b][6] + a1.w * vsh[1][b][7] +
                 a2.x * vsh[1][b][8];
      kA[j] = f2key(a2.y + cvsh[0][b] - 2.0f * dA);
      kB[j] = f2key(a2.y + cvsh[1][b] - 2.0f * dB);
    }
    wave_top64<PER>(kA, &cand[0][wave * 64], lane);
    wave_top64<PER>(kB, &cand[1][wave * 64], lane);
  }
  __syncthreads();
  if (wave < 2) {
    float s = final_sum64(cand[wave], lane);
    if (lane == 0)
      ws[(is_intra ? WS_CS_INTRA : WS_CS_INTER) + c0 + wave] = s;
  }
}

// ---------------- kernel 4: final deterministic reduce ----------------
__global__ __launch_bounds__(256) void reduce_kernel(
    const float* __restrict__ ws, float* __restrict__ out) {
  __shared__ double sbuf[256];
  __shared__ double tA;
  int tid = threadIdx.x;
  double sa = 0.0, sb = 0.0;
  for (int i = tid; i < N_; i += 256) {
    sa += (double)ws[WS_CS_INTRA + i];
    sb += (double)ws[WS_CS_INTER + i];
  }
  sbuf[tid] = sa;
  __syncthreads();
  for (int off = 128; off > 0; off >>= 1) {
    if (tid < off) sbuf[tid] += sbuf[tid + off];
    __syncthreads();
  }
  if (tid == 0) tA = sbuf[0];
  __syncthreads();
  sbuf[tid] = sb;
  __syncthreads();
  for (int off = 128; off > 0; off >>= 1) {
    if (tid < off) sbuf[tid] += sbuf[tid + off];
    __syncthreads();
  }
  if (tid == 0) {
    double denom = (double)N_ * (double)K_;
    out[0] = (float)(tA / denom - 0.1 * (sbuf[0] / denom));
  }
}

extern "C" void kernel_launch(void* const* d_in, const int* in_sizes, int n_in,
                              void* d_out, int out_size, void* d_ws,
                              size_t ws_size, hipStream_t stream) {
  const float* outputs = (const float*)d_in[0];
  const float* targets = (const float*)d_in[1];
  const void* mask = d_in[2];
  float* ws = (float*)d_ws;

  hipLaunchKernelGGL(stats_part_kernel, dim3(NPART), dim3(256), 0, stream,
                     targets, mask, ws);
  hipLaunchKernelGGL(stats_fin_kernel, dim3(1), dim3(64), 0, stream, ws);
  hipLaunchKernelGGL(pre_kernel, dim3((BM_ + BN_ + 255) / 256), dim3(256), 0,
                     stream, outputs, targets, mask, ws);
  hipLaunchKernelGGL(select_kernel, dim3(N_), dim3(TSEL), 0, stream,
                     outputs, ws, ws);
  hipLaunchKernelGGL(reduce_kernel, dim3(1), dim3(256), 0, stream, ws,
                     (float*)d_out);
}